// Round 8
// baseline (125.858 us; speedup 1.0000x reference)
//
#include <hip/hip_runtime.h>
#include <hip/hip_bf16.h>
#include <math.h>

// ---------------- problem constants ----------------
#define N_ROWS 8192
#define DIM    512
#define NCLS   64
#define BM     128   // tile rows/cols
#define BK     64    // K step
#define NKT    (DIM / BK)                    // 8 K-tiles
#define NTILE  (N_ROWS / BM)                 // 64 tile-blocks per side
#define NTRI   (NTILE * (NTILE + 1) / 2)     // 2080 upper-tri tiles = 8 * 260
#define NSLOT  NTILE                         // 64 partial slots
#define M_CONST 14.285714285714286f          // 1/T : the fixed max-shift (diagonal)
#define L2E     1.4426950408889634f          // log2(e)
#define M2_CONST 20.60992915555662f          // log2(e)/T (shift in exp2 units)
#define SCALE2  4.539815541256959f           // sqrt(log2(e)/T): MFMA outputs log2e*sim

using bf16x8 = __attribute__((ext_vector_type(8))) short;
using f32x4  = __attribute__((ext_vector_type(4))) float;

static __device__ inline unsigned short f2bf(float x) {
  unsigned u = __float_as_uint(x);
  unsigned r = u + 0x7FFFu + ((u >> 16) & 1u);   // RNE
  return (unsigned short)(r >> 16);
}

// ---- kernel 1: L2-normalize rows, scale by sqrt(log2e/T), cast bf16; fused hist
__global__ __launch_bounds__(256) void normalize_rows(const float* __restrict__ proj,
                                                      const int* __restrict__ tgt,
                                                      unsigned short* __restrict__ outb,
                                                      int* __restrict__ hist) {
  const int row  = blockIdx.x * 4 + (threadIdx.x >> 6);
  const int lane = threadIdx.x & 63;
  if (lane == 0) atomicAdd(&hist[tgt[row]], 1);    // hist fused (hist pre-zeroed)
  const float4* src = (const float4*)(proj + (size_t)row * DIM);
  float4 a = src[lane * 2];
  float4 b = src[lane * 2 + 1];
  float ss = a.x*a.x + a.y*a.y + a.z*a.z + a.w*a.w
           + b.x*b.x + b.y*b.y + b.z*b.z + b.w*b.w;
#pragma unroll
  for (int off = 1; off < 64; off <<= 1) ss += __shfl_xor(ss, off);
  const float scale = SCALE2 / fmaxf(sqrtf(ss), 1e-12f);
  float v[8] = {a.x, a.y, a.z, a.w, b.x, b.y, b.z, b.w};
  unsigned short h[8];
#pragma unroll
  for (int i = 0; i < 8; ++i) h[i] = f2bf(v[i] * scale);
  uint4 packed;
  packed.x = (unsigned)h[0] | ((unsigned)h[1] << 16);
  packed.y = (unsigned)h[2] | ((unsigned)h[3] << 16);
  packed.z = (unsigned)h[4] | ((unsigned)h[5] << 16);
  packed.w = (unsigned)h[6] | ((unsigned)h[7] << 16);
  *(uint4*)(outb + (size_t)row * DIM + lane * 8) = packed;
}

// ---- kernel 2: 128^2 tile GEMM, 8 waves (wave-tile 64x32), fused epilogue -----
// R2's proven 2-phase schedule (1 barrier/tile) with 2x the resident waves:
// 512 threads, LDS ~71KB -> 2 blocks/CU = 16 waves/CU. Per-wave regs halved
// (acc = 32 f32) -> no spills under the 128-VGPR cap of launch_bounds(512,4).
// Swizzle: pre-swizzled global source (key r&7), linear gload_lds dest,
// matching XOR on ds_read (measured 0 conflicts in R2).
__global__ __launch_bounds__(512, 4) void supcon_tile(const unsigned short* __restrict__ p16,
                                                      const int* __restrict__ tgt,
                                                      float* __restrict__ dpart,
                                                      float* __restrict__ spart) {
  // XCD-chunked bijective remap (2080 = 8*260), then triangle decode
  const int logical = ((int)blockIdx.x & 7) * (NTRI / 8) + ((int)blockIdx.x >> 3);
  int rem = logical, br = 0;
  while (rem >= NTILE - br) { rem -= NTILE - br; ++br; }
  const int bc = br + rem;

  __shared__ short As[2][BM * BK];   // 2 x 16 KB
  __shared__ short Bs[2][BM * BK];   // 2 x 16 KB
  __shared__ int   tgr[BM], tgc[BM];
  __shared__ float redE[4][BM], redS[4][BM];     // row partials per wn
  __shared__ float redEc[2][BM], redSc[2][BM];   // col partials per wm

  const int tid  = threadIdx.x;
  const int lane = tid & 63;
  const int wid  = tid >> 6;          // 0..7
  const int wm = wid >> 2, wn = wid & 3;          // 2 row-halves x 4 col-strips
  const int lhi = lane >> 4, llo = lane & 15;

  const size_t rowA0 = (size_t)br * BM;
  const size_t rowB0 = (size_t)bc * BM;

  // staging: 1024 granules (16B) per array; thread covers g = tid, tid+512.
  // LDS dest linear in g (wave-uniform base + lane*16); source granule swizzled.
#define STAGE(BUF, KT) do {                                                         \
  _Pragma("unroll")                                                                 \
  for (int j = 0; j < 2; ++j) {                                                     \
    const int g  = tid + j * 512;                                                   \
    const int r  = g >> 3, gp = g & 7;                                              \
    const int gl = gp ^ (r & 7);                                                    \
    const unsigned short* sA = p16 + (rowA0 + r) * DIM + (KT) * BK + gl * 8;        \
    const unsigned short* sB = p16 + (rowB0 + r) * DIM + (KT) * BK + gl * 8;        \
    __builtin_amdgcn_global_load_lds((const __attribute__((address_space(1))) void*)sA, \
        (__attribute__((address_space(3))) void*)&As[BUF][g * 8], 16, 0, 0);        \
    __builtin_amdgcn_global_load_lds((const __attribute__((address_space(1))) void*)sB, \
        (__attribute__((address_space(3))) void*)&Bs[BUF][g * 8], 16, 0, 0);        \
  }                                                                                 \
} while (0)

  STAGE(0, 0);
  if (tid < BM)            tgr[tid] = tgt[br * BM + tid];
  else if (tid < 2 * BM)   tgc[tid - BM] = tgt[bc * BM + (tid - BM)];

  f32x4 zero = {0.f, 0.f, 0.f, 0.f};
  f32x4 acc[4][2];
#pragma unroll
  for (int i = 0; i < 4; ++i)
#pragma unroll
    for (int j = 0; j < 2; ++j) acc[i][j] = zero;

  __syncthreads();   // prologue stage drained

  int cur = 0;
  for (int kt = 0; kt < NKT; ++kt) {
    if (kt + 1 < NKT) STAGE(cur ^ 1, kt + 1);   // prefetch next K-tile
#pragma unroll
    for (int ks = 0; ks < 2; ++ks) {
      bf16x8 af[4], bfr[2];
#pragma unroll
      for (int mi = 0; mi < 4; ++mi) {
        const int Ra = wm * 64 + mi * 16 + llo;
        af[mi] = *(const bf16x8*)&As[cur][Ra * BK + (((ks * 4 + lhi) ^ (Ra & 7)) * 8)];
      }
#pragma unroll
      for (int ni = 0; ni < 2; ++ni) {
        const int Rb = wn * 32 + ni * 16 + llo;
        bfr[ni] = *(const bf16x8*)&Bs[cur][Rb * BK + (((ks * 4 + lhi) ^ (Rb & 7)) * 8)];
      }
#pragma unroll
      for (int mi = 0; mi < 4; ++mi)
#pragma unroll
        for (int ni = 0; ni < 2; ++ni)
          acc[mi][ni] = __builtin_amdgcn_mfma_f32_16x16x32_bf16(af[mi], bfr[ni], acc[mi][ni], 0, 0, 0);
    }
    __syncthreads();   // drains prefetch vmcnt + compute lgkm; buffer ready
    cur ^= 1;
  }
#undef STAGE

  // ---- epilogue (exp2 units): acc = log2e*sim; e = exp2(acc - M2) ------------
  const bool diag = (br == bc);
  const int tc0 = tgc[wn * 32 + llo];
  const int tc1 = tgc[wn * 32 + 16 + llo];
  float ecol[2] = {0.f, 0.f};
  float scol[2] = {0.f, 0.f};

#pragma unroll
  for (int mi = 0; mi < 4; ++mi) {
#pragma unroll
    for (int rg = 0; rg < 4; ++rg) {
      const int rin  = wm * 64 + mi * 16 + lhi * 4 + rg;   // row within tile
      const int trow = tgr[rin];
      float esum = 0.f, ssum = 0.f;
#pragma unroll
      for (int ni = 0; ni < 2; ++ni) {
        const int cin = wn * 32 + ni * 16 + llo;           // col within tile
        const float x = acc[mi][ni][rg];                   // log2e * sim
        const bool self = diag && (rin == cin);
        const float e = self ? 0.f : __builtin_amdgcn_exp2f(x - M2_CONST);
        const bool pos = (!self) && (trow == (ni ? tc1 : tc0));
        const float sv = pos ? x : 0.f;
        esum += e;  ssum += sv;
        ecol[ni] += e;  scol[ni] += sv;
      }
#pragma unroll
      for (int off = 1; off < 16; off <<= 1) {
        esum += __shfl_xor(esum, off);
        ssum += __shfl_xor(ssum, off);
      }
      if (llo == 0) { redE[wn][rin] = esum; redS[wn][rin] = ssum; }
    }
  }
  if (!diag) {  // transpose contribution: column sums -> rows of block bc
#pragma unroll
    for (int ni = 0; ni < 2; ++ni) {
      float ec = ecol[ni], sc = scol[ni];
      ec += __shfl_xor(ec, 16); ec += __shfl_xor(ec, 32);
      sc += __shfl_xor(sc, 16); sc += __shfl_xor(sc, 32);
      if (lhi == 0) {
        redEc[wm][wn * 32 + ni * 16 + llo] = ec;
        redSc[wm][wn * 32 + ni * 16 + llo] = sc;
      }
    }
  }
  __syncthreads();

  // cross-wave reduce; each [slot][row] cell written by exactly one block:
  // row-path of (br,bc) under slot bc; col-path under slot br (br!=bc).
  if (tid < BM) {
    const float e = redE[0][tid] + redE[1][tid] + redE[2][tid] + redE[3][tid];
    const float s = redS[0][tid] + redS[1][tid] + redS[2][tid] + redS[3][tid];
    dpart[(size_t)bc * N_ROWS + rowA0 + tid] = e;
    spart[(size_t)bc * N_ROWS + rowA0 + tid] = s;
  } else if (tid < 2 * BM && !diag) {
    const int c = tid - BM;
    dpart[(size_t)br * N_ROWS + rowB0 + c] = redEc[0][c] + redEc[1][c];
    spart[(size_t)br * N_ROWS + rowB0 + c] = redSc[0][c] + redSc[1][c];
  }
}

// ---- kernel 3: combine partials -> per-sample loss ----------------------------
__global__ __launch_bounds__(256) void combine_loss(const float* __restrict__ dpart,
                                                    const float* __restrict__ spart,
                                                    const int* __restrict__ tgt,
                                                    const int* __restrict__ hist,
                                                    float* __restrict__ out) {
  __shared__ float dsh[4][64], ssh[4][64];
  const int lane = threadIdx.x & 63;
  const int g    = threadIdx.x >> 6;
  const int r    = blockIdx.x * 64 + lane;
  float d = 0.f, s = 0.f;
  for (int k = g * (NSLOT / 4); k < (g + 1) * (NSLOT / 4); ++k) {
    d += dpart[(size_t)k * N_ROWS + r];
    s += spart[(size_t)k * N_ROWS + r];
  }
  dsh[g][lane] = d; ssh[g][lane] = s;
  __syncthreads();
  if (g == 0) {
    d = dsh[0][lane] + dsh[1][lane] + dsh[2][lane] + dsh[3][lane];
    s = ssh[0][lane] + ssh[1][lane] + ssh[2][lane] + ssh[3][lane];
    const int cnt = hist[tgt[r]] - 1;
    // s is in log2e*sim units -> divide back by L2E
    out[r] = (cnt > 0) ? (s / (L2E * (float)cnt) - M_CONST - logf(d + 1e-8f)) : 0.f;
  }
}

// ---------------- launcher ----------------
extern "C" void kernel_launch(void* const* d_in, const int* in_sizes, int n_in,
                              void* d_out, int out_size, void* d_ws, size_t ws_size,
                              hipStream_t stream) {
  const float* proj = (const float*)d_in[0];
  const int*   tgt  = (const int*)d_in[1];
  float* out = (float*)d_out;

  char* ws = (char*)d_ws;
  unsigned short* p16  = (unsigned short*)ws;                        // 8 MB
  float* dpart = (float*)(ws + (size_t)8  * 1024 * 1024);            // 2 MB (64 x 8192)
  float* spart = (float*)(ws + (size_t)10 * 1024 * 1024);            // 2 MB
  int*   hist  = (int*)(ws + (size_t)12 * 1024 * 1024);              // 256 B

  (void)hipMemsetAsync(hist, 0, NCLS * sizeof(int), stream);         // graph-capturable
  normalize_rows<<<N_ROWS / 4, 256, 0, stream>>>(proj, tgt, p16, hist);
  supcon_tile<<<NTRI, 512, 0, stream>>>(p16, tgt, dpart, spart);
  combine_loss<<<N_ROWS / 64, 256, 0, stream>>>(dpart, spart, tgt, hist, out);
}

// Round 9
// 91.700 us; speedup vs baseline: 1.3725x; 1.3725x over previous
//
#include <hip/hip_runtime.h>
#include <hip/hip_bf16.h>
#include <math.h>

// ---------------- problem constants ----------------
#define N_ROWS 8192
#define DIM    512
#define NCLS   64
#define BM     128   // tile rows/cols
#define BK     64    // K step
#define NKT    (DIM / BK)                    // 8 K-tiles
#define NTILE  (N_ROWS / BM)                 // 64 tile-blocks per side
#define NTRI   (NTILE * (NTILE + 1) / 2)     // 2080 upper-tri tiles = 8 * 260
#define NSLOT  NTILE                         // 64 partial slots
#define M_CONST 14.285714285714286f          // 1/T : the fixed max-shift (diagonal)
#define L2E     1.4426950408889634f          // log2(e)
#define M2_CONST 20.60992915555662f          // log2(e)/T (shift in exp2 units)
#define SCALE2  4.539815541256959f           // sqrt(log2(e)/T): MFMA outputs log2e*sim

using bf16x8 = __attribute__((ext_vector_type(8))) short;
using f32x4  = __attribute__((ext_vector_type(4))) float;

static __device__ inline unsigned short f2bf(float x) {
  unsigned u = __float_as_uint(x);
  unsigned r = u + 0x7FFFu + ((u >> 16) & 1u);   // RNE
  return (unsigned short)(r >> 16);
}

// ---- kernel 1: L2-normalize rows, scale by sqrt(log2e/T), cast bf16 -----------
__global__ __launch_bounds__(256) void normalize_rows(const float* __restrict__ proj,
                                                      unsigned short* __restrict__ outb) {
  const int row  = blockIdx.x * 4 + (threadIdx.x >> 6);
  const int lane = threadIdx.x & 63;
  const float4* src = (const float4*)(proj + (size_t)row * DIM);
  float4 a = src[lane * 2];
  float4 b = src[lane * 2 + 1];
  float ss = a.x*a.x + a.y*a.y + a.z*a.z + a.w*a.w
           + b.x*b.x + b.y*b.y + b.z*b.z + b.w*b.w;
#pragma unroll
  for (int off = 1; off < 64; off <<= 1) ss += __shfl_xor(ss, off);
  const float scale = SCALE2 / fmaxf(sqrtf(ss), 1e-12f);
  float v[8] = {a.x, a.y, a.z, a.w, b.x, b.y, b.z, b.w};
  unsigned short h[8];
#pragma unroll
  for (int i = 0; i < 8; ++i) h[i] = f2bf(v[i] * scale);
  uint4 packed;
  packed.x = (unsigned)h[0] | ((unsigned)h[1] << 16);
  packed.y = (unsigned)h[2] | ((unsigned)h[3] << 16);
  packed.z = (unsigned)h[4] | ((unsigned)h[5] << 16);
  packed.w = (unsigned)h[6] | ((unsigned)h[7] << 16);
  *(uint4*)(outb + (size_t)row * DIM + lane * 8) = packed;
}

// ---- kernel 2: class histogram, wave-privatized (R2's proven version) ---------
__global__ __launch_bounds__(1024) void class_hist(const int* __restrict__ tgt,
                                                   int* __restrict__ hist) {
  __shared__ int h[16][NCLS];
  const int wid = threadIdx.x >> 6;
  const int lane = threadIdx.x & 63;
  if (lane < NCLS) h[wid][lane] = 0;
  __syncthreads();
  for (int i = threadIdx.x; i < N_ROWS; i += 1024) atomicAdd(&h[wid][tgt[i]], 1);
  __syncthreads();
  if (threadIdx.x < NCLS) {
    int s = 0;
#pragma unroll
    for (int w = 0; w < 16; ++w) s += h[w][threadIdx.x];
    hist[threadIdx.x] = s;
  }
}

// ---- kernel 3: 128^2 tile GEMM, 8 waves, counted-vmcnt depth-2 pipeline -------
// R8's spill-free geometry (512 thr, wave-tile 64x32, LDS 71KB -> 2 blk/CU)
// with the T3/T4 schedule isolated: per K-tile { s_barrier (prev reads done) ->
// STAGE(t+1) -> s_waitcnt vmcnt(4) (waits ONLY tile t's 4 loads, issued a full
// tile ago; t+1's stay in flight) -> s_barrier (tile t's writes landed) ->
// compute }. vmcnt never drains to 0 mid-loop; kt unrolled (static buf index).
__global__ __launch_bounds__(512, 4) void supcon_tile(const unsigned short* __restrict__ p16,
                                                      const int* __restrict__ tgt,
                                                      float* __restrict__ dpart,
                                                      float* __restrict__ spart) {
  // XCD-chunked bijective remap (2080 = 8*260), then triangle decode
  const int logical = ((int)blockIdx.x & 7) * (NTRI / 8) + ((int)blockIdx.x >> 3);
  int rem = logical, br = 0;
  while (rem >= NTILE - br) { rem -= NTILE - br; ++br; }
  const int bc = br + rem;

  __shared__ short As[2][BM * BK];   // 2 x 16 KB
  __shared__ short Bs[2][BM * BK];   // 2 x 16 KB
  __shared__ int   tgr[BM], tgc[BM];
  __shared__ float redE[4][BM], redS[4][BM];     // row partials per wn
  __shared__ float redEc[2][BM], redSc[2][BM];   // col partials per wm

  const int tid  = threadIdx.x;
  const int lane = tid & 63;
  const int wid  = tid >> 6;          // 0..7
  const int wm = wid >> 2, wn = wid & 3;          // 2 row-halves x 4 col-strips
  const int lhi = lane >> 4, llo = lane & 15;

  const size_t rowA0 = (size_t)br * BM;
  const size_t rowB0 = (size_t)bc * BM;

  // staging: 1024 granules (16B) per array; thread covers g = tid, tid+512.
  // LDS dest linear in g (wave-uniform base + lane*16); source granule swizzled.
  // 4 gload_lds per thread per K-tile (2 A + 2 B).
#define STAGE(BUF, KT) do {                                                         \
  _Pragma("unroll")                                                                 \
  for (int j = 0; j < 2; ++j) {                                                     \
    const int g  = tid + j * 512;                                                   \
    const int r  = g >> 3, gp = g & 7;                                              \
    const int gl = gp ^ (r & 7);                                                    \
    const unsigned short* sA = p16 + (rowA0 + r) * DIM + (KT) * BK + gl * 8;        \
    const unsigned short* sB = p16 + (rowB0 + r) * DIM + (KT) * BK + gl * 8;        \
    __builtin_amdgcn_global_load_lds((const __attribute__((address_space(1))) void*)sA, \
        (__attribute__((address_space(3))) void*)&As[BUF][g * 8], 16, 0, 0);        \
    __builtin_amdgcn_global_load_lds((const __attribute__((address_space(1))) void*)sB, \
        (__attribute__((address_space(3))) void*)&Bs[BUF][g * 8], 16, 0, 0);        \
  }                                                                                 \
} while (0)

  STAGE(0, 0);
  if (tid < BM)            tgr[tid] = tgt[br * BM + tid];
  else if (tid < 2 * BM)   tgc[tid - BM] = tgt[bc * BM + (tid - BM)];

  f32x4 zero = {0.f, 0.f, 0.f, 0.f};
  f32x4 acc[4][2];
#pragma unroll
  for (int i = 0; i < 4; ++i)
#pragma unroll
    for (int j = 0; j < 2; ++j) acc[i][j] = zero;

  __syncthreads();   // prologue: full drain; buf0 + targets ready

#pragma unroll
  for (int kt = 0; kt < NKT; ++kt) {
    const int cur = kt & 1, nxt = cur ^ 1;

    if (kt > 0) {
      // all waves finished reading buf[nxt] during tile kt-1 -> safe to overwrite
      __builtin_amdgcn_s_barrier();
      __builtin_amdgcn_sched_barrier(0);
    }
    if (kt + 1 < NKT) {
      STAGE(nxt, kt + 1);                              // 4 loads, stay in flight
      asm volatile("s_waitcnt vmcnt(4)" ::: "memory"); // waits ONLY tile kt's loads
    } else {
      asm volatile("s_waitcnt vmcnt(0)" ::: "memory"); // last tile: drain
    }
    __builtin_amdgcn_sched_barrier(0);
    __builtin_amdgcn_s_barrier();                      // all waves' loads(kt) landed
    __builtin_amdgcn_sched_barrier(0);

#pragma unroll
    for (int ks = 0; ks < 2; ++ks) {
      bf16x8 af[4], bfr[2];
#pragma unroll
      for (int mi = 0; mi < 4; ++mi) {
        const int Ra = wm * 64 + mi * 16 + llo;
        af[mi] = *(const bf16x8*)&As[cur][Ra * BK + (((ks * 4 + lhi) ^ (Ra & 7)) * 8)];
      }
#pragma unroll
      for (int ni = 0; ni < 2; ++ni) {
        const int Rb = wn * 32 + ni * 16 + llo;
        bfr[ni] = *(const bf16x8*)&Bs[cur][Rb * BK + (((ks * 4 + lhi) ^ (Rb & 7)) * 8)];
      }
#pragma unroll
      for (int mi = 0; mi < 4; ++mi)
#pragma unroll
        for (int ni = 0; ni < 2; ++ni)
          acc[mi][ni] = __builtin_amdgcn_mfma_f32_16x16x32_bf16(af[mi], bfr[ni], acc[mi][ni], 0, 0, 0);
    }
  }
#undef STAGE

  // ---- epilogue (exp2 units): acc = log2e*sim; e = exp2(acc - M2) ------------
  const bool diag = (br == bc);
  const int tc0 = tgc[wn * 32 + llo];
  const int tc1 = tgc[wn * 32 + 16 + llo];
  float ecol[2] = {0.f, 0.f};
  float scol[2] = {0.f, 0.f};

#pragma unroll
  for (int mi = 0; mi < 4; ++mi) {
#pragma unroll
    for (int rg = 0; rg < 4; ++rg) {
      const int rin  = wm * 64 + mi * 16 + lhi * 4 + rg;   // row within tile
      const int trow = tgr[rin];
      float esum = 0.f, ssum = 0.f;
#pragma unroll
      for (int ni = 0; ni < 2; ++ni) {
        const int cin = wn * 32 + ni * 16 + llo;           // col within tile
        const float x = acc[mi][ni][rg];                   // log2e * sim
        const bool self = diag && (rin == cin);
        const float e = self ? 0.f : __builtin_amdgcn_exp2f(x - M2_CONST);
        const bool pos = (!self) && (trow == (ni ? tc1 : tc0));
        const float sv = pos ? x : 0.f;
        esum += e;  ssum += sv;
        ecol[ni] += e;  scol[ni] += sv;
      }
#pragma unroll
      for (int off = 1; off < 16; off <<= 1) {
        esum += __shfl_xor(esum, off);
        ssum += __shfl_xor(ssum, off);
      }
      if (llo == 0) { redE[wn][rin] = esum; redS[wn][rin] = ssum; }
    }
  }
  if (!diag) {  // transpose contribution: column sums -> rows of block bc
#pragma unroll
    for (int ni = 0; ni < 2; ++ni) {
      float ec = ecol[ni], sc = scol[ni];
      ec += __shfl_xor(ec, 16); ec += __shfl_xor(ec, 32);
      sc += __shfl_xor(sc, 16); sc += __shfl_xor(sc, 32);
      if (lhi == 0) {
        redEc[wm][wn * 32 + ni * 16 + llo] = ec;
        redSc[wm][wn * 32 + ni * 16 + llo] = sc;
      }
    }
  }
  __syncthreads();

  // cross-wave reduce; each [slot][row] cell written by exactly one block:
  // row-path of (br,bc) under slot bc; col-path under slot br (br!=bc).
  if (tid < BM) {
    const float e = redE[0][tid] + redE[1][tid] + redE[2][tid] + redE[3][tid];
    const float s = redS[0][tid] + redS[1][tid] + redS[2][tid] + redS[3][tid];
    dpart[(size_t)bc * N_ROWS + rowA0 + tid] = e;
    spart[(size_t)bc * N_ROWS + rowA0 + tid] = s;
  } else if (tid < 2 * BM && !diag) {
    const int c = tid - BM;
    dpart[(size_t)br * N_ROWS + rowB0 + c] = redEc[0][c] + redEc[1][c];
    spart[(size_t)br * N_ROWS + rowB0 + c] = redSc[0][c] + redSc[1][c];
  }
}

// ---- kernel 4: combine partials -> per-sample loss ----------------------------
__global__ __launch_bounds__(256) void combine_loss(const float* __restrict__ dpart,
                                                    const float* __restrict__ spart,
                                                    const int* __restrict__ tgt,
                                                    const int* __restrict__ hist,
                                                    float* __restrict__ out) {
  __shared__ float dsh[4][64], ssh[4][64];
  const int lane = threadIdx.x & 63;
  const int g    = threadIdx.x >> 6;
  const int r    = blockIdx.x * 64 + lane;
  float d = 0.f, s = 0.f;
  for (int k = g * (NSLOT / 4); k < (g + 1) * (NSLOT / 4); ++k) {
    d += dpart[(size_t)k * N_ROWS + r];
    s += spart[(size_t)k * N_ROWS + r];
  }
  dsh[g][lane] = d; ssh[g][lane] = s;
  __syncthreads();
  if (g == 0) {
    d = dsh[0][lane] + dsh[1][lane] + dsh[2][lane] + dsh[3][lane];
    s = ssh[0][lane] + ssh[1][lane] + ssh[2][lane] + ssh[3][lane];
    const int cnt = hist[tgt[r]] - 1;
    // s is in log2e*sim units -> divide back by L2E
    out[r] = (cnt > 0) ? (s / (L2E * (float)cnt) - M_CONST - logf(d + 1e-8f)) : 0.f;
  }
}

// ---------------- launcher ----------------
extern "C" void kernel_launch(void* const* d_in, const int* in_sizes, int n_in,
                              void* d_out, int out_size, void* d_ws, size_t ws_size,
                              hipStream_t stream) {
  const float* proj = (const float*)d_in[0];
  const int*   tgt  = (const int*)d_in[1];
  float* out = (float*)d_out;

  char* ws = (char*)d_ws;
  unsigned short* p16  = (unsigned short*)ws;                        // 8 MB
  float* dpart = (float*)(ws + (size_t)8  * 1024 * 1024);            // 2 MB (64 x 8192)
  float* spart = (float*)(ws + (size_t)10 * 1024 * 1024);            // 2 MB
  int*   hist  = (int*)(ws + (size_t)12 * 1024 * 1024);              // 256 B

  normalize_rows<<<N_ROWS / 4, 256, 0, stream>>>(proj, p16);
  class_hist<<<1, 1024, 0, stream>>>(tgt, hist);
  supcon_tile<<<NTRI, 512, 0, stream>>>(p16, tgt, dpart, spart);
  combine_loss<<<N_ROWS / 64, 256, 0, stream>>>(dpart, spart, tgt, hist, out);
}